// Round 6
// baseline (83.788 us; speedup 1.0000x reference)
//
#include <hip/hip_runtime.h>
#include <hip/hip_bf16.h>

// ---------- types ----------
typedef __attribute__((ext_vector_type(8))) short  short8;
typedef __attribute__((ext_vector_type(4))) float  f32x4;

#define NCLS 10
#define TILE 128
#define TPB  1024          // 16 waves
#define NQ   10            // upper-triangular 16x16 quads of 64x64 Gram
#define PPB  (NCLS * NQ * 256)   // floats per block of partials (25600)
#define CH   16            // reduction chunks

#define AS1 __attribute__((address_space(1)))
#define AS3 __attribute__((address_space(3)))

// fp32 -> bf16 round-to-nearest-even
static __device__ inline unsigned short f2bf(float x) {
    unsigned u = __builtin_bit_cast(unsigned, x);
    return (unsigned short)((u + 0x7FFFu + ((u >> 16) & 1u)) >> 16);
}

// ---------- DMA one tile (h fp32 + yhat) into LDS; d-permuted source ----------
// fp32 LDS layout: word(n,d) = n*64 + (d ^ ((n&7)<<3)); rows >= N clamped to N-1
// (their data is masked to zero later; y overridden to -1 in convert).
static __device__ __forceinline__ void issue_tile(
        const float* __restrict__ h, const int* __restrict__ yhat,
        float* fsb, int* yb, long t, long N, int wid, int lane) {
#pragma unroll
    for (int i = 0; i < 2; ++i) {
        const int C  = wid * 128 + i * 64 + lane;   // 16B chunk id, 0..2047
        const int n  = C >> 4;                      // tile row
        const int cc = C & 15;                      // chunk within row
        long row = t * TILE + n;
        if (row > N - 1) row = N - 1;
        const float* gp = h + row * 64 + ((cc << 2) ^ ((n & 7) << 3));
        __builtin_amdgcn_global_load_lds((const AS1 float*)gp,
                                         (AS3 float*)(fsb + (wid * 2 + i) * 256),
                                         16, 0, 0);
    }
    if (wid == 0 && lane < 32) {   // 128 ints = 32 lanes x 16B (N%4==0 assumed)
        long y0 = t * TILE + lane * 4;
        if (y0 > N - 4) y0 = N - 4;
        __builtin_amdgcn_global_load_lds((const AS1 int*)(yhat + y0),
                                         (AS3 int*)yb, 16, 0, 0);
    }
}

// ---------- compute: NS k-slices for one class, both MFMA operands masked ----------
template<int NS>
static __device__ __forceinline__ void compute_range(
        const char* hsb, const char* mkb,
        int cls, int ks0, int hi, int col, f32x4 (&acc)[NQ]) {
    const int cb = col << 8;     // col*256 bytes (d-row stride of [64][128] bf16)
    const int c7 = col & 7;
#pragma unroll
    for (int s = 0; s < NS; ++s) {
        const int ks = ks0 + s;
        const short8 m = *reinterpret_cast<const short8*>(mkb + cls * 256 + ks * 64 + hi * 16);
        const int x = ((ks * 4 + hi) ^ c7) << 4;
        short8 am[4];
#pragma unroll
        for (int nb = 0; nb < 4; ++nb) {
            short8 r = *reinterpret_cast<const short8*>(hsb + nb * 4096 + cb + x);
            am[nb] = r & m;
        }
        acc[0] = __builtin_amdgcn_mfma_f32_16x16x32_bf16(am[0], am[0], acc[0], 0, 0, 0);
        acc[1] = __builtin_amdgcn_mfma_f32_16x16x32_bf16(am[0], am[1], acc[1], 0, 0, 0);
        acc[2] = __builtin_amdgcn_mfma_f32_16x16x32_bf16(am[0], am[2], acc[2], 0, 0, 0);
        acc[3] = __builtin_amdgcn_mfma_f32_16x16x32_bf16(am[0], am[3], acc[3], 0, 0, 0);
        acc[4] = __builtin_amdgcn_mfma_f32_16x16x32_bf16(am[1], am[1], acc[4], 0, 0, 0);
        acc[5] = __builtin_amdgcn_mfma_f32_16x16x32_bf16(am[1], am[2], acc[5], 0, 0, 0);
        acc[6] = __builtin_amdgcn_mfma_f32_16x16x32_bf16(am[1], am[3], acc[6], 0, 0, 0);
        acc[7] = __builtin_amdgcn_mfma_f32_16x16x32_bf16(am[2], am[2], acc[7], 0, 0, 0);
        acc[8] = __builtin_amdgcn_mfma_f32_16x16x32_bf16(am[2], am[3], acc[8], 0, 0, 0);
        acc[9] = __builtin_amdgcn_mfma_f32_16x16x32_bf16(am[3], am[3], acc[9], 0, 0, 0);
    }
}

// ---------- kernel 1: masked Grams via MFMA; 3-deep DMA ring, counted vmcnt ----------
// partials: [G][NCLS][NQ][256] f32; cntp: [G][16] int. Both fully overwritten.
__global__ __launch_bounds__(TPB, 4) void HL_gram(
        const float* __restrict__ h, const int* __restrict__ yhat,
        float* __restrict__ partials, int* __restrict__ cntp,
        long N, int ntiles, int G) {
    __shared__ __align__(16) float          fs[3][TILE * 64];     // 96 KB fp32 ring
    __shared__ __align__(16) unsigned short hs[2][64 * TILE];     // 32 KB bf16
    __shared__ __align__(16) unsigned short mk[2][NCLS * TILE];   // 5 KB masks
    __shared__ __align__(16) int            ylds[3][TILE];        // 1.5 KB
    __shared__ int cntlds[16];

    const int tid  = threadIdx.x;
    const int wid  = tid >> 6;
    const int lane = tid & 63;
    const int hi   = lane >> 4;
    const int col  = lane & 15;

    if (tid < 16) cntlds[tid] = 0;
    asm volatile("s_waitcnt lgkmcnt(0)" ::: "memory");

    // wave roles: classes 0-5 split across (w, w+10); 6-9 full range
    int cls, ks0, ns;
    if      (wid < 6)  { cls = wid;      ks0 = 0; ns = 2; }
    else if (wid < 10) { cls = wid;      ks0 = 0; ns = 4; }
    else               { cls = wid - 10; ks0 = 2; ns = 2; }

    f32x4 acc[NQ];
#pragma unroll
    for (int q = 0; q < NQ; ++q) acc[q] = (f32x4){0.f, 0.f, 0.f, 0.f};

    const int bid = blockIdx.x;
    const int K   = (ntiles - bid + G - 1) / G;   // tiles for this block (>=1)

    // prologue: up to 3 tiles in flight
#pragma unroll
    for (int kk = 0; kk < 3; ++kk)
        if (kk < K)
            issue_tile(h, yhat, &fs[kk][0], &ylds[kk][0], bid + (long)kk * G, N, wid, lane);

    for (int k = 0; k < K; ++k) {
        const long t  = bid + (long)k * G;
        const int  bk = k % 3;      // fp32/y ring slot
        const int  hk = k & 1;      // bf16/mask double-buffer slot
        const int  r  = (K - 1 - k) > 2 ? 2 : (K - 1 - k);   // tiles to keep in flight

        // bar1: own-wave counted wait for tile k's DMA, then converge
        if (wid == 0) {
            if (r == 2)      asm volatile("s_waitcnt vmcnt(6)" ::: "memory");
            else if (r == 1) asm volatile("s_waitcnt vmcnt(3)" ::: "memory");
            else             asm volatile("s_waitcnt vmcnt(0)" ::: "memory");
        } else {
            if (r == 2)      asm volatile("s_waitcnt vmcnt(4)" ::: "memory");
            else if (r == 1) asm volatile("s_waitcnt vmcnt(2)" ::: "memory");
            else             asm volatile("s_waitcnt vmcnt(0)" ::: "memory");
        }
        __builtin_amdgcn_s_barrier();

        // ---- convert: thread owns (d=lane, rows wid*8..+7); conflict-free ----
        {
            const float* fsb = &fs[bk][0];
            short8 w;
#pragma unroll
            for (int j = 0; j < 8; ++j) {
                const float x = fsb[(wid * 8 + j) * 64 + (lane ^ (j << 3))];
                w[j] = (short)f2bf(x);
            }
            *reinterpret_cast<short8*>(
                (char*)&hs[hk][0] + lane * 256 + ((wid ^ (lane & 7)) << 4)) = w;
        }
        if (tid < TILE) {
            int y = ylds[bk][tid];
            if (t * TILE + tid >= N) y = -1;   // clamped DMA rows -> no class
#pragma unroll
            for (int c = 0; c < NCLS; ++c) {
                mk[hk][c * TILE + tid] = (y == c) ? (unsigned short)0xFFFFu : (unsigned short)0u;
                unsigned long long b = __ballot(y == c);
                if (lane == 0) atomicAdd(&cntlds[c], __popcll(b));
            }
        }

        asm volatile("s_waitcnt lgkmcnt(0)" ::: "memory");
        __builtin_amdgcn_s_barrier();   // bar2: bf16 + masks visible

        // refill ring slot bk (its readers are done) -- keeps 3 tiles in flight
        if (k + 3 < K)
            issue_tile(h, yhat, &fs[bk][0], &ylds[bk][0], bid + (long)(k + 3) * G, N, wid, lane);

        // ---- compute ----
        if (ns == 4) compute_range<4>((const char*)&hs[hk][0], (const char*)&mk[hk][0],
                                      cls, 0,   hi, col, acc);
        else         compute_range<2>((const char*)&hs[hk][0], (const char*)&mk[hk][0],
                                      cls, ks0, hi, col, acc);
    }

    // ---------- merge split-class halves (waves 10-15 -> waves 0-5) ----------
    float* xch = (float*)&fs[0][0];
#pragma unroll
    for (int qq = 0; qq < NQ; qq += 2) {
        __syncthreads();
        if (wid >= 10) {
            float* dst = xch + (wid - 10) * 512;
            *reinterpret_cast<f32x4*>(dst + (lane << 2))       = acc[qq];
            *reinterpret_cast<f32x4*>(dst + 256 + (lane << 2)) = acc[qq + 1];
        }
        __syncthreads();
        if (wid < 6) {
            const float* src = xch + wid * 512;
            acc[qq]     += *reinterpret_cast<const f32x4*>(src + (lane << 2));
            acc[qq + 1] += *reinterpret_cast<const f32x4*>(src + 256 + (lane << 2));
        }
    }

    // ---------- stream partials (waves 0-9) + per-block counts ----------
    if (wid < NCLS) {
        float* pb = partials + (size_t)bid * PPB + (size_t)wid * (NQ * 256);
#pragma unroll
        for (int q = 0; q < NQ; ++q)
            *reinterpret_cast<f32x4*>(pb + q * 256 + (lane << 2)) = acc[q];
    }
    if (tid < NCLS) cntp[bid * 16 + tid] = cntlds[tid];
}

// ---------- kernel 2: chunked block-reduction of partials (atomic-free) ----------
// rpart: [CH][NCLS*NQ][256] f32, fully overwritten. Also zeroes out[0].
__global__ void HL_reduce(const float* __restrict__ partials, float* __restrict__ rpart,
                          float* __restrict__ out, int G, int CS) {
    const int idx = blockIdx.x * blockDim.x + threadIdx.x;
    if (blockIdx.x == 0 && threadIdx.x == 0) out[0] = 0.f;
    if (idx >= CH * NCLS * NQ * 64) return;
    const int ch = idx / (NCLS * NQ * 64);
    const int r  = idx % (NCLS * NQ * 64);
    const int cq = r >> 6;
    const int l  = r & 63;

    int b0 = ch * CS;
    int b1 = b0 + CS; if (b1 > G) b1 = G;

    f32x4 s = (f32x4){0.f, 0.f, 0.f, 0.f};
    const float* p = partials + (size_t)cq * 256 + (l << 2);
    for (int b = b0; b < b1; ++b)
        s += *reinterpret_cast<const f32x4*>(p + (size_t)b * PPB);

    *reinterpret_cast<f32x4*>(rpart + ((size_t)ch * (NCLS * NQ) + cq) * 256 + (l << 2)) = s;
}

// ---------- kernel 3: counts + M = 0.5*G/cnt + I; loss += 0.5*logdet ----------
__global__ __launch_bounds__(64, 1) void HL_chol(
        const float* __restrict__ rpart, const int* __restrict__ cntp,
        float* __restrict__ out, int G) {
    __shared__ float M[64][68];
    __shared__ float lcol[64];
    const int cls = blockIdx.x;
    const int i   = threadIdx.x;   // lane 0..63

    int c = 0;
    for (int b = i; b < G; b += 64) c += cntp[b * 16 + cls];
#pragma unroll
    for (int off = 32; off > 0; off >>= 1) c += __shfl_xor(c, off);
    const float inv = 0.5f / (float)c;

    const int QMB[NQ] = {0,0,0,0,1,1,1,2,2,3};
    const int QNB[NQ] = {0,1,2,3,1,2,3,2,3,3};
    const float* rp = rpart + (size_t)cls * (NQ * 256);
#pragma unroll
    for (int q = 0; q < NQ; ++q) {
        f32x4 s = (f32x4){0.f, 0.f, 0.f, 0.f};
#pragma unroll
        for (int ch = 0; ch < CH; ++ch)
            s += *reinterpret_cast<const f32x4*>(rp + (size_t)ch * (NCLS * NQ * 256) + q * 256 + (i << 2));
        const int row0 = QMB[q] * 16 + ((i >> 4) << 2);
        const int colo = QNB[q] * 16 + (i & 15);
#pragma unroll
        for (int rr = 0; rr < 4; ++rr) {
            M[row0 + rr][colo] = s[rr];
            M[colo][row0 + rr] = s[rr];
        }
    }
    __syncthreads();

    float row[64];
#pragma unroll
    for (int c2 = 0; c2 < 64; ++c2)
        row[c2] = M[i][c2] * inv + (c2 == i ? 1.0f : 0.0f);

#pragma unroll
    for (int j = 0; j < 64; ++j) {
        const float piv = __shfl(row[j], j);
        const float li  = row[j] * rsqrtf(piv);
        lcol[i] = li;
        __syncthreads();
#pragma unroll
        for (int c2 = j + 1; c2 < 64; ++c2)
            row[c2] -= li * lcol[c2];
        __syncthreads();
    }

    float slog = 0.f;
#pragma unroll
    for (int j = 0; j < 64; ++j)
        if (i == j) slog = __logf(row[j]);
    slog += __shfl_down(slog, 32); slog += __shfl_down(slog, 16);
    slog += __shfl_down(slog, 8);  slog += __shfl_down(slog, 4);
    slog += __shfl_down(slog, 2);  slog += __shfl_down(slog, 1);
    if (i == 0) atomicAdd(out, 0.5f * slog);
}

// ---------- launcher ----------
extern "C" void kernel_launch(void* const* d_in, const int* in_sizes, int n_in,
                              void* d_out, int out_size, void* d_ws, size_t ws_size,
                              hipStream_t stream) {
    const float* h    = (const float*)d_in[0];
    const int*   yhat = (const int*)d_in[1];
    const long   N    = in_sizes[1];
    float* out = (float*)d_out;

    // ws layout: [rpart CH*100*256 f32][cntp G*16 int][partials G*PPB f32]
    const size_t rpart_sz = (size_t)CH * NCLS * NQ * 256 * sizeof(float);
    const size_t cntp_off = rpart_sz;

    const int ntiles = (int)((N + TILE - 1) / TILE);
    int G = 256;
    {
        const size_t perG = 64 + (size_t)PPB * sizeof(float);
        if (ws_size > rpart_sz) {
            size_t maxG = (ws_size - rpart_sz) / perG;
            if ((size_t)G > maxG) G = (int)maxG;
        } else G = 1;
        if (G < 1) G = 1;
    }
    if (G > ntiles) G = ntiles;

    const size_t partials_off = cntp_off + (size_t)G * 16 * sizeof(int);
    float* rpart    = (float*)d_ws;
    int*   cntp     = (int*)((char*)d_ws + cntp_off);
    float* partials = (float*)((char*)d_ws + partials_off);

    HL_gram<<<G, TPB, 0, stream>>>(h, yhat, partials, cntp, N, ntiles, G);

    int CS = (G + CH - 1) / CH;
    const int rthreads = CH * NCLS * NQ * 64;
    HL_reduce<<<(rthreads + 255) / 256, 256, 0, stream>>>(partials, rpart, out, G, CS);

    HL_chol<<<NCLS, 64, 0, stream>>>(rpart, cntp, out, G);
}